// Round 2
// baseline (9222.590 us; speedup 1.0000x reference)
//
#include <hip/hip_runtime.h>
#include <cmath>

#define B_   128
#define T_   100
#define IN_  512
#define H_   1024
#define E_   8
#define HH_  512
#define GIN_ 5
#define GH_  8
#define KC_  128

__device__ __forceinline__ float sigf(float x) { return 1.0f / (1.0f + expf(-x)); }

#define DOT4(a, xv, wv)                                              \
  a = fmaf((xv).x, (wv).x, a); a = fmaf((xv).y, (wv).y, a);          \
  a = fmaf((xv).z, (wv).z, a); a = fmaf((xv).w, (wv).w, a);

__device__ __forceinline__ void gridbar(unsigned* c) {
  __syncthreads();
  if (threadIdx.x == 0) {
    __threadfence();   // release: push h stores through L2 -> LLC
    __hip_atomic_fetch_add(c, 1u, __ATOMIC_RELAXED, __HIP_MEMORY_SCOPE_AGENT);
    while (__hip_atomic_load(c, __ATOMIC_RELAXED, __HIP_MEMORY_SCOPE_AGENT) < gridDim.x) {
      __builtin_amdgcn_s_sleep(1);
    }
    __threadfence();   // acquire: invalidate L1/L2 so remote h writes are seen
  }
  __syncthreads();
}

// Persistent main-GRU kernel: 256 blocks x 512 threads, 1 block/CU (128 KB LDS).
// Block tile: 4 j-columns x 128 batches, full K=1536 split across 8 waves (192 k each).
// Wave-private double-buffered LDS staging (no block barriers in k-loop).
__global__ __launch_bounds__(512, 2) void gru_persist(
    const float* __restrict__ X,
    const float* __restrict__ wih, const float* __restrict__ whh,
    const float* __restrict__ bih, const float* __restrict__ bhh,
    float* __restrict__ hb0, float* __restrict__ hb1,
    unsigned* __restrict__ barr)
{
  extern __shared__ float4 sb4[];   // 8192 float4 = 128 KB
  const int tid  = threadIdx.x;
  const int lane = tid & 63;
  const int ks   = __builtin_amdgcn_readfirstlane(tid >> 6);   // K-split id 0..7
  const int j0   = blockIdx.x << 2;

  // staging addressing: buffer layout [b(128)][slot(4 quads)], slot = q ^ (b&3)
  const int l2 = lane >> 2;            // b sub-row within 16-row group
  const int lq = lane & 3;             // source k-quad
  const int wslot = lq ^ (l2 & 3);
  float4* const region = sb4 + ks * 1024;         // wave-private 16 KB (2 x 512 quads)
  const int wq = (l2 << 2) + wslot;               // write quad (i=0)
  const int rq = lane << 2;                       // read row base quad (b=lane)

  // reduce-phase mapping
  const int rjj = tid >> 7;            // 0..3
  const int rb  = tid & 127;
  const int rj  = j0 + rjj;
  const float bir = bih[rj], biz = bih[H_ + rj], bin = bih[2 * H_ + rj];
  const float bhr = bhh[rj], bhz = bhh[H_ + rj], bhn = bhh[2 * H_ + rj];

  // uniform weight row pointers
  const float *wrx[4], *wzx[4], *wnx[4], *wrh[4], *wzh[4], *wnh[4];
  #pragma unroll
  for (int jj = 0; jj < 4; ++jj) {
    wrx[jj] = wih + (size_t)(j0 + jj) * IN_;
    wzx[jj] = wih + (size_t)(H_ + j0 + jj) * IN_;
    wnx[jj] = wih + (size_t)(2 * H_ + j0 + jj) * IN_;
    wrh[jj] = whh + (size_t)(j0 + jj) * H_;
    wzh[jj] = whh + (size_t)(H_ + j0 + jj) * H_;
    wnh[jj] = whh + (size_t)(2 * H_ + j0 + jj) * H_;
  }

  float4 st[8];

  for (int t = 0; t < T_; ++t) {
    const float* __restrict__ hp = (t & 1) ? hb1 : hb0;
    float*       __restrict__ hn = (t & 1) ? hb0 : hb1;

    float ar[4][2] = {}, az[4][2] = {}, anx[4][2] = {}, anh[4][2] = {};

    // ---- prolog: stage sub-chunk 0 into buf 0
    {
      const int k0 = ks * 192;
      if (k0 < IN_) {
        #pragma unroll
        for (int i = 0; i < 8; ++i)
          st[i] = *(const float4*)(X + ((size_t)(i * 16 + l2) * T_ + t) * IN_ + k0 + lq * 4);
      } else {
        #pragma unroll
        for (int i = 0; i < 8; ++i)
          st[i] = *(const float4*)(hp + (size_t)(i * 16 + l2) * H_ + (k0 - IN_) + lq * 4);
      }
      #pragma unroll
      for (int i = 0; i < 8; ++i) region[i * 64 + wq] = st[i];
    }

    // ---- k-loop: 12 sub-chunks of 16 k, wave-private dbuf, no barriers
    for (int sc = 0; sc < 12; ++sc) {
      const int k0 = ks * 192 + sc * 16;
      if (sc < 11) {                       // prefetch next sub-chunk into regs
        const int kn = k0 + 16;
        if (kn < IN_) {
          #pragma unroll
          for (int i = 0; i < 8; ++i)
            st[i] = *(const float4*)(X + ((size_t)(i * 16 + l2) * T_ + t) * IN_ + kn + lq * 4);
        } else {
          #pragma unroll
          for (int i = 0; i < 8; ++i)
            st[i] = *(const float4*)(hp + (size_t)(i * 16 + l2) * H_ + (kn - IN_) + lq * 4);
        }
      }
      const float4* rb4 = region + (sc & 1) * 512;
      if (k0 < IN_) {
        #pragma unroll
        for (int q = 0; q < 4; ++q) {
          const int sl = q ^ (lane & 3);
          float4 x0 = rb4[rq + sl];
          float4 x1 = rb4[rq + sl + 256];
          const int kk = k0 + q * 4;
          #pragma unroll
          for (int jj = 0; jj < 4; ++jj) {
            float4 wr = *(const float4*)(wrx[jj] + kk);
            float4 wz = *(const float4*)(wzx[jj] + kk);
            float4 wn = *(const float4*)(wnx[jj] + kk);
            DOT4(ar[jj][0], x0, wr); DOT4(ar[jj][1], x1, wr);
            DOT4(az[jj][0], x0, wz); DOT4(az[jj][1], x1, wz);
            DOT4(anx[jj][0], x0, wn); DOT4(anx[jj][1], x1, wn);
          }
        }
      } else {
        #pragma unroll
        for (int q = 0; q < 4; ++q) {
          const int sl = q ^ (lane & 3);
          float4 x0 = rb4[rq + sl];
          float4 x1 = rb4[rq + sl + 256];
          const int kk = k0 - IN_ + q * 4;
          #pragma unroll
          for (int jj = 0; jj < 4; ++jj) {
            float4 wr = *(const float4*)(wrh[jj] + kk);
            float4 wz = *(const float4*)(wzh[jj] + kk);
            float4 wn = *(const float4*)(wnh[jj] + kk);
            DOT4(ar[jj][0], x0, wr); DOT4(ar[jj][1], x1, wr);
            DOT4(az[jj][0], x0, wz); DOT4(az[jj][1], x1, wz);
            DOT4(anh[jj][0], x0, wn); DOT4(anh[jj][1], x1, wn);
          }
        }
      }
      if (sc < 11) {                       // write prefetched regs into other buffer
        float4* wb4 = region + ((sc + 1) & 1) * 512;
        #pragma unroll
        for (int i = 0; i < 8; ++i) wb4[i * 64 + wq] = st[i];
      }
    }

    // ---- cross-wave K reduction through LDS
    __syncthreads();   // all staging reads done; safe to reuse LDS
    #pragma unroll
    for (int jj = 0; jj < 4; ++jj) {
      sb4[(ks * 4 + jj) * 128 + lane]      = make_float4(ar[jj][0], az[jj][0], anx[jj][0], anh[jj][0]);
      sb4[(ks * 4 + jj) * 128 + 64 + lane] = make_float4(ar[jj][1], az[jj][1], anx[jj][1], anh[jj][1]);
    }
    __syncthreads();

    float sr = 0.f, sz = 0.f, sx = 0.f, sh = 0.f;
    #pragma unroll
    for (int k2 = 0; k2 < 8; ++k2) {
      float4 v = sb4[(k2 * 4 + rjj) * 128 + rb];
      sr += v.x; sz += v.y; sx += v.z; sh += v.w;
    }
    float r = sigf(sr + bir + bhr);
    float z = sigf(sz + biz + bhz);
    float n = tanhf(sx + bin + r * (sh + bhn));
    float hpv = hp[(size_t)rb * H_ + rj];
    hn[(size_t)rb * H_ + rj] = (1.f - z) * n + z * hpv;

    gridbar(barr + t);   // entry syncthreads also protects LDS reuse next step
  }
}

// Gating GRUs: one wave per batch, gate-per-lane (24 gates), all state in regs.
__global__ __launch_bounds__(64, 1) void gating_kernel(
    const float* __restrict__ X,
    const float* __restrict__ gwih0, const float* __restrict__ gwhh0,
    const float* __restrict__ gbih0, const float* __restrict__ gbhh0,
    const float* __restrict__ gwih1, const float* __restrict__ gwhh1,
    const float* __restrict__ gbih1, const float* __restrict__ gbhh1,
    float* __restrict__ omega)
{
  const int b = blockIdx.x;
  const int g = threadIdx.x;
  const int u = g & 7;
  float wi0[GIN_] = {}, wh0[GH_] = {}, wi1[GH_] = {}, wh1[GH_] = {};
  float bi0 = 0.f, bh0 = 0.f, bi1 = 0.f, bh1 = 0.f;
  if (g < 3 * GH_) {
    #pragma unroll
    for (int i = 0; i < GIN_; ++i) wi0[i] = gwih0[g * GIN_ + i];
    #pragma unroll
    for (int k = 0; k < GH_; ++k) { wh0[k] = gwhh0[g * GH_ + k]; wi1[k] = gwih1[g * GH_ + k]; wh1[k] = gwhh1[g * GH_ + k]; }
    bi0 = gbih0[g]; bh0 = gbhh0[g]; bi1 = gbih1[g]; bh1 = gbhh1[g];
  }
  float h0[GH_] = {}, h1[GH_] = {};
  for (int t = 0; t < T_; ++t) {
    float xt[GIN_];
    #pragma unroll
    for (int i = 0; i < GIN_; ++i) xt[i] = X[((size_t)b * T_ + t) * IN_ + (IN_ - GIN_) + i];
    // layer 0
    float px = bi0, ph = bh0;
    #pragma unroll
    for (int i = 0; i < GIN_; ++i) px = fmaf(xt[i], wi0[i], px);
    #pragma unroll
    for (int k = 0; k < GH_; ++k) ph = fmaf(h0[k], wh0[k], ph);
    float s = px + ph;
    float s_r = __shfl(s, u);
    float s_z = __shfl(s, 8 + u);
    float nval = tanhf(px + sigf(s_r) * ph);        // valid on lanes 16..23
    float zval = sigf(s_z);
    float hnew = (1.f - zval) * nval + zval * h0[u];
    #pragma unroll
    for (int k = 0; k < GH_; ++k) h0[k] = __shfl(hnew, 16 + k);
    // layer 1 (input = new h0)
    float px1 = bi1, ph1 = bh1;
    #pragma unroll
    for (int k = 0; k < GH_; ++k) px1 = fmaf(h0[k], wi1[k], px1);
    #pragma unroll
    for (int k = 0; k < GH_; ++k) ph1 = fmaf(h1[k], wh1[k], ph1);
    float s1 = px1 + ph1;
    float s1r = __shfl(s1, u);
    float s1z = __shfl(s1, 8 + u);
    float n1 = tanhf(px1 + sigf(s1r) * ph1);
    float z1 = sigf(s1z);
    float h1new = (1.f - z1) * n1 + z1 * h1[u];
    #pragma unroll
    for (int k = 0; k < GH_; ++k) h1[k] = __shfl(h1new, 16 + k);
  }
  if (g < GH_) {
    float m = h1[0];
    #pragma unroll
    for (int k = 1; k < GH_; ++k) m = fmaxf(m, h1[k]);
    float sum = 0.f;
    #pragma unroll
    for (int k = 0; k < GH_; ++k) sum += expf(h1[k] - m);
    omega[b * GH_ + g] = expf(h1[g] - m) / sum;
  }
}

// MoE layer: out[b,j] = act( sum_e omega[b,e] * (dot(in[b,:],w[e,:,j]) + bias[e,j]) )
__global__ __launch_bounds__(256, 2) void moe_kernel(
    const float* __restrict__ in, const float* __restrict__ w,
    const float* __restrict__ bias, const float* __restrict__ omega,
    float* __restrict__ out, int K, int act)
{
  __shared__ float4 lin4[64 * 32];
  __shared__ float  ldsw[E_ * 4 * KC_];
  const int tid  = threadIdx.x;
  const int bh   = blockIdx.x & 1;
  const int jt   = blockIdx.x >> 1;
  const int wv   = tid >> 6;
  const int lane = tid & 63;
  const int j0   = jt * 4;
  const int j    = __builtin_amdgcn_readfirstlane(j0 + wv);
  const int b    = bh * 64 + lane;

  float acc[E_] = {0.f,0.f,0.f,0.f,0.f,0.f,0.f,0.f};
  const float4* row4 = &lin4[lane * 32];
  const int nch = K / KC_;

  for (int c = 0; c < nch; ++c) {
    __syncthreads();
    const int k0 = c * KC_;
    #pragma unroll
    for (int it = 0; it < 8; ++it) {
      int f = it * 256 + tid;
      int bb = f >> 5, q = f & 31;
      float4 v = *(const float4*)(in + (size_t)(bh * 64 + bb) * K + k0 + q * 4);
      lin4[bb * 32 + ((q & 24) | ((q ^ bb) & 7))] = v;
    }
    #pragma unroll
    for (int it = 0; it < 4; ++it) {
      int f = it * 256 + tid;
      int e = f >> 7, k = f & 127;
      float4 v = *(const float4*)(w + ((size_t)e * K + k0 + k) * HH_ + j0);
      ldsw[(e * 4 + 0) * KC_ + k] = v.x;
      ldsw[(e * 4 + 1) * KC_ + k] = v.y;
      ldsw[(e * 4 + 2) * KC_ + k] = v.z;
      ldsw[(e * 4 + 3) * KC_ + k] = v.w;
    }
    __syncthreads();
    #pragma unroll 2
    for (int q = 0; q < 32; ++q) {
      float4 xv = row4[(q & 24) | ((q ^ lane) & 7)];
      #pragma unroll
      for (int e = 0; e < E_; ++e) {
        const float4 wq = *(const float4*)&ldsw[(e * 4 + wv) * KC_ + 4 * q];
        acc[e] = fmaf(xv.x, wq.x, acc[e]);
        acc[e] = fmaf(xv.y, wq.y, acc[e]);
        acc[e] = fmaf(xv.z, wq.z, acc[e]);
        acc[e] = fmaf(xv.w, wq.w, acc[e]);
      }
    }
  }

  float om[E_];
  #pragma unroll
  for (int e = 0; e < E_; ++e) om[e] = omega[b * E_ + e];
  float v = 0.f;
  #pragma unroll
  for (int e = 0; e < E_; ++e) v = fmaf(om[e], acc[e] + bias[e * HH_ + j], v);
  if (act == 0) v = (v > 0.f) ? v : expm1f(v);
  else          v = fminf(fmaxf(v, 0.f), 1.f);
  out[(size_t)b * HH_ + j] = v;
}

extern "C" void kernel_launch(void* const* d_in, const int* in_sizes, int n_in,
                              void* d_out, int out_size, void* d_ws, size_t ws_size,
                              hipStream_t stream) {
  (void)in_sizes; (void)n_in; (void)out_size; (void)ws_size;
  const float* X     = (const float*)d_in[0];
  const float* gwih0 = (const float*)d_in[1];
  const float* gwhh0 = (const float*)d_in[2];
  const float* gbih0 = (const float*)d_in[3];
  const float* gbhh0 = (const float*)d_in[4];
  const float* gwih1 = (const float*)d_in[5];
  const float* gwhh1 = (const float*)d_in[6];
  const float* gbih1 = (const float*)d_in[7];
  const float* gbhh1 = (const float*)d_in[8];
  const float* mwih  = (const float*)d_in[9];
  const float* mwhh  = (const float*)d_in[10];
  const float* mbih  = (const float*)d_in[11];
  const float* mbhh  = (const float*)d_in[12];
  const float* w1    = (const float*)d_in[13];
  const float* b1    = (const float*)d_in[14];
  const float* w2    = (const float*)d_in[15];
  const float* b2    = (const float*)d_in[16];
  const float* w3    = (const float*)d_in[17];
  const float* b3    = (const float*)d_in[18];

  float* ws = (float*)d_ws;
  unsigned* barr = (unsigned*)ws;                 // 100 slots (256 floats reserved)
  float* h0 = ws + 256;
  float* h1 = h0 + (size_t)B_ * H_;
  float* om = h1 + (size_t)B_ * H_;
  float* a1 = om + B_ * GH_;
  float* a2 = a1 + (size_t)B_ * HH_;

  // zero: barrier slots + h0 (initial hidden state)
  hipMemsetAsync(d_ws, 0, (256 + (size_t)B_ * H_) * sizeof(float), stream);
  hipFuncSetAttribute((const void*)gru_persist,
                      hipFuncAttributeMaxDynamicSharedMemorySize, 131072);

  gating_kernel<<<128, 64, 0, stream>>>(X, gwih0, gwhh0, gbih0, gbhh0,
                                        gwih1, gwhh1, gbih1, gbhh1, om);
  gru_persist<<<256, 512, 131072, stream>>>(X, mwih, mwhh, mbih, mbhh, h0, h1, barr);
  moe_kernel<<<256, 256, 0, stream>>>(h0, w1, b1, om, a1, H_, 0);
  moe_kernel<<<256, 256, 0, stream>>>(a1, w2, b2, om, a2, HH_, 0);
  moe_kernel<<<256, 256, 0, stream>>>(a2, w3, b3, om, (float*)d_out, HH_, 1);
}

// Round 3
// 7792.661 us; speedup vs baseline: 1.1835x; 1.1835x over previous
//
#include <hip/hip_runtime.h>
#include <cmath>

#define B_   128
#define T_   100
#define IN_  512
#define H_   1024
#define E_   8
#define HH_  512
#define GIN_ 5
#define GH_  8

__device__ __forceinline__ float sigf(float x) { return 1.0f / (1.0f + expf(-x)); }

#define DOT4(a, xv, wv)                                              \
  a = fmaf((xv).x, (wv).x, a); a = fmaf((xv).y, (wv).y, a);          \
  a = fmaf((xv).z, (wv).z, a); a = fmaf((xv).w, (wv).w, a);

__device__ __forceinline__ void gridbar(unsigned* c) {
  __syncthreads();
  if (threadIdx.x == 0) {
    __threadfence();   // release: push h stores through L2 -> LLC
    __hip_atomic_fetch_add(c, 1u, __ATOMIC_RELAXED, __HIP_MEMORY_SCOPE_AGENT);
    while (__hip_atomic_load(c, __ATOMIC_RELAXED, __HIP_MEMORY_SCOPE_AGENT) < gridDim.x) {
      __builtin_amdgcn_s_sleep(1);
    }
    __threadfence();   // acquire: invalidate L1/L2 so remote h writes are seen
  }
  __syncthreads();
}

// Transpose X[b][t][0:512] -> XT4[t][kq][b] (float4 per (kq,b)).
__global__ __launch_bounds__(256) void xt_kernel(
    const float* __restrict__ X, float4* __restrict__ XT4)
{
  int idx = blockIdx.x * 256 + threadIdx.x;     // over 100*128*128
  int b  = idx & 127;
  int kq = (idx >> 7) & 127;
  int t  = idx >> 14;
  XT4[idx] = *(const float4*)(X + ((size_t)b * T_ + t) * IN_ + kq * 4);
}

// Persistent main GRU: 256 blocks x 512 threads, 1 block/CU (90 KB LDS).
// Block: 4 j-cols x 128 batches. Waves: (jl 0..3) x (k-half 0..1).
// Weights in LDS (loaded once). x/h read coalesced from quad-major global.
__global__ __launch_bounds__(512, 2) void gru_persist(
    const float* __restrict__ X, const float4* __restrict__ XT4, int use_xt,
    const float* __restrict__ wih, const float* __restrict__ whh,
    const float* __restrict__ bih, const float* __restrict__ bhh,
    float* __restrict__ hA, float* __restrict__ hB,   // h4T [H/4][128] float4
    unsigned* __restrict__ barr)
{
  extern __shared__ float sw[];                       // 4*3*1536 floats
  float4* const sw4  = (float4*)sw;
  float4* const red4 = (float4*)(sw + 4 * 3 * 1536);  // [2][4][128] float4

  const int tid  = threadIdx.x;
  const int lane = tid & 63;
  const int w    = __builtin_amdgcn_readfirstlane(tid >> 6);
  const int jl   = w & 3;
  const int kh   = w >> 2;
  const int j0   = blockIdx.x << 2;

  // ---- one-time: weights -> LDS  (rows j0..j0+3, gates r,z,n; k-merged x|h)
  for (int idx = tid; idx < 4608; idx += 512) {
    int jlw = idx / 1152;
    int rem = idx - jlw * 1152;
    int g   = rem / 384;
    int kq  = rem - g * 384;
    float4 v;
    if (kq < 128) v = *(const float4*)(wih + (size_t)(g * H_ + j0 + jlw) * IN_ + kq * 4);
    else          v = *(const float4*)(whh + (size_t)(g * H_ + j0 + jlw) * H_ + (kq - 128) * 4);
    sw4[(jlw * 3 + g) * 384 + kq] = v;
  }

  // epilogue mapping + per-thread biases (fixed j per thread)
  const int ejl = tid >> 7;
  const int ebb = tid & 127;
  const int ej  = j0 + ejl;
  const float bir = bih[ej], biz = bih[H_ + ej], bin = bih[2 * H_ + ej];
  const float bhr = bhh[ej], bhz = bhh[H_ + ej], bhn = bhh[2 * H_ + ej];

  const int wb_r = (jl * 3 + 0) * 384;
  const int wb_z = (jl * 3 + 1) * 384;
  const int wb_n = (jl * 3 + 2) * 384;

  __syncthreads();

  for (int t = 0; t < T_; ++t) {
    const float4* __restrict__ hp4 = (const float4*)((t & 1) ? hB : hA);
    float*        __restrict__ hn  = (t & 1) ? hA : hB;

    float ar0 = 0.f, az0 = 0.f, ax0 = 0.f, ah0 = 0.f;
    float ar1 = 0.f, az1 = 0.f, ax1 = 0.f, ah1 = 0.f;

    if (kh == 0) {
      // x-part: k 0..511
      if (use_xt) {
        const float4* xt = XT4 + (size_t)t * 128 * 128;
        #pragma unroll 4
        for (int kq = 0; kq < 128; ++kq) {
          float4 x0 = xt[kq * 128 + lane];
          float4 x1 = xt[kq * 128 + lane + 64];
          float4 wr = sw4[wb_r + kq], wz = sw4[wb_z + kq], wn = sw4[wb_n + kq];
          DOT4(ar0, x0, wr); DOT4(ar1, x1, wr);
          DOT4(az0, x0, wz); DOT4(az1, x1, wz);
          DOT4(ax0, x0, wn); DOT4(ax1, x1, wn);
        }
      } else {
        const float* xr0 = X + ((size_t)lane * T_ + t) * IN_;
        const float* xr1 = X + ((size_t)(lane + 64) * T_ + t) * IN_;
        #pragma unroll 4
        for (int kq = 0; kq < 128; ++kq) {
          float4 x0 = *(const float4*)(xr0 + kq * 4);
          float4 x1 = *(const float4*)(xr1 + kq * 4);
          float4 wr = sw4[wb_r + kq], wz = sw4[wb_z + kq], wn = sw4[wb_n + kq];
          DOT4(ar0, x0, wr); DOT4(ar1, x1, wr);
          DOT4(az0, x0, wz); DOT4(az1, x1, wz);
          DOT4(ax0, x0, wn); DOT4(ax1, x1, wn);
        }
      }
      // h-part: k 512..767
      #pragma unroll 4
      for (int kq = 128; kq < 192; ++kq) {
        float4 x0 = hp4[(kq - 128) * 128 + lane];
        float4 x1 = hp4[(kq - 128) * 128 + lane + 64];
        float4 wr = sw4[wb_r + kq], wz = sw4[wb_z + kq], wn = sw4[wb_n + kq];
        DOT4(ar0, x0, wr); DOT4(ar1, x1, wr);
        DOT4(az0, x0, wz); DOT4(az1, x1, wz);
        DOT4(ah0, x0, wn); DOT4(ah1, x1, wn);
      }
    } else {
      // h-part: k 768..1535
      #pragma unroll 4
      for (int kq = 192; kq < 384; ++kq) {
        float4 x0 = hp4[(kq - 128) * 128 + lane];
        float4 x1 = hp4[(kq - 128) * 128 + lane + 64];
        float4 wr = sw4[wb_r + kq], wz = sw4[wb_z + kq], wn = sw4[wb_n + kq];
        DOT4(ar0, x0, wr); DOT4(ar1, x1, wr);
        DOT4(az0, x0, wz); DOT4(az1, x1, wz);
        DOT4(ah0, x0, wn); DOT4(ah1, x1, wn);
      }
    }

    // ---- cross-k-half reduce via LDS
    red4[(kh * 4 + jl) * 128 + lane]      = make_float4(ar0, az0, ax0, ah0);
    red4[(kh * 4 + jl) * 128 + lane + 64] = make_float4(ar1, az1, ax1, ah1);
    __syncthreads();

    float4 v0 = red4[(0 + ejl) * 128 + ebb];
    float4 v1 = red4[(4 + ejl) * 128 + ebb];
    float sr = v0.x + v1.x, sz = v0.y + v1.y;
    float sx = v0.z + v1.z, sh = v0.w + v1.w;
    float r = sigf(sr + bir + bhr);
    float z = sigf(sz + biz + bhz);
    float n = tanhf(sx + bin + r * (sh + bhn));
    int hidx = (((ej >> 2) * 128 + ebb) << 2) + (ej & 3);
    float hpv = ((const float*)hp4)[hidx];
    hn[hidx] = (1.f - z) * n + z * hpv;

    gridbar(barr + t);
  }
}

// Final h4T -> hfin[b][k]
__global__ __launch_bounds__(256) void hfin_kernel(
    const float* __restrict__ h4, float* __restrict__ out)
{
  int idx = blockIdx.x * 256 + threadIdx.x;   // over 128*1024
  int b = idx >> 10, k = idx & 1023;
  out[idx] = h4[(((k >> 2) * 128 + b) << 2) + (k & 3)];
}

// Gating GRUs: one wave per batch, gate-per-lane (24 gates), all state in regs.
__global__ __launch_bounds__(64, 1) void gating_kernel(
    const float* __restrict__ X,
    const float* __restrict__ gwih0, const float* __restrict__ gwhh0,
    const float* __restrict__ gbih0, const float* __restrict__ gbhh0,
    const float* __restrict__ gwih1, const float* __restrict__ gwhh1,
    const float* __restrict__ gbih1, const float* __restrict__ gbhh1,
    float* __restrict__ omega)
{
  const int b = blockIdx.x;
  const int g = threadIdx.x;
  const int u = g & 7;
  float wi0[GIN_] = {}, wh0[GH_] = {}, wi1[GH_] = {}, wh1[GH_] = {};
  float bi0 = 0.f, bh0 = 0.f, bi1 = 0.f, bh1 = 0.f;
  if (g < 3 * GH_) {
    #pragma unroll
    for (int i = 0; i < GIN_; ++i) wi0[i] = gwih0[g * GIN_ + i];
    #pragma unroll
    for (int k = 0; k < GH_; ++k) { wh0[k] = gwhh0[g * GH_ + k]; wi1[k] = gwih1[g * GH_ + k]; wh1[k] = gwhh1[g * GH_ + k]; }
    bi0 = gbih0[g]; bh0 = gbhh0[g]; bi1 = gbih1[g]; bh1 = gbhh1[g];
  }
  float h0[GH_] = {}, h1[GH_] = {};
  for (int t = 0; t < T_; ++t) {
    float xt[GIN_];
    #pragma unroll
    for (int i = 0; i < GIN_; ++i) xt[i] = X[((size_t)b * T_ + t) * IN_ + (IN_ - GIN_) + i];
    float px = bi0, ph = bh0;
    #pragma unroll
    for (int i = 0; i < GIN_; ++i) px = fmaf(xt[i], wi0[i], px);
    #pragma unroll
    for (int k = 0; k < GH_; ++k) ph = fmaf(h0[k], wh0[k], ph);
    float s = px + ph;
    float s_r = __shfl(s, u);
    float s_z = __shfl(s, 8 + u);
    float nval = tanhf(px + sigf(s_r) * ph);
    float zval = sigf(s_z);
    float hnew = (1.f - zval) * nval + zval * h0[u];
    #pragma unroll
    for (int k = 0; k < GH_; ++k) h0[k] = __shfl(hnew, 16 + k);
    float px1 = bi1, ph1 = bh1;
    #pragma unroll
    for (int k = 0; k < GH_; ++k) px1 = fmaf(h0[k], wi1[k], px1);
    #pragma unroll
    for (int k = 0; k < GH_; ++k) ph1 = fmaf(h1[k], wh1[k], ph1);
    float s1 = px1 + ph1;
    float s1r = __shfl(s1, u);
    float s1z = __shfl(s1, 8 + u);
    float n1 = tanhf(px1 + sigf(s1r) * ph1);
    float z1 = sigf(s1z);
    float h1new = (1.f - z1) * n1 + z1 * h1[u];
    #pragma unroll
    for (int k = 0; k < GH_; ++k) h1[k] = __shfl(h1new, 16 + k);
  }
  if (g < GH_) {
    float m = h1[0];
    #pragma unroll
    for (int k = 1; k < GH_; ++k) m = fmaxf(m, h1[k]);
    float sum = 0.f;
    #pragma unroll
    for (int k = 0; k < GH_; ++k) sum += expf(h1[k] - m);
    omega[b * GH_ + g] = expf(h1[g] - m) / sum;
  }
}

// MoE layer: out[b,j] = act( sum_e omega[b,e] * (dot(in[b,:],w[e,:,j]) + bias[e,j]) )
__global__ __launch_bounds__(256, 2) void moe_kernel(
    const float* __restrict__ in, const float* __restrict__ w,
    const float* __restrict__ bias, const float* __restrict__ omega,
    float* __restrict__ out, int K, int act)
{
  __shared__ float4 lin4[64 * 32];
  __shared__ float  ldsw[E_ * 4 * 128];
  const int tid  = threadIdx.x;
  const int bh   = blockIdx.x & 1;
  const int jt   = blockIdx.x >> 1;
  const int wv   = tid >> 6;
  const int lane = tid & 63;
  const int j0   = jt * 4;
  const int j    = __builtin_amdgcn_readfirstlane(j0 + wv);
  const int b    = bh * 64 + lane;

  float acc[E_] = {0.f,0.f,0.f,0.f,0.f,0.f,0.f,0.f};
  const float4* row4 = &lin4[lane * 32];
  const int nch = K / 128;

  for (int c = 0; c < nch; ++c) {
    __syncthreads();
    const int k0 = c * 128;
    #pragma unroll
    for (int it = 0; it < 8; ++it) {
      int f = it * 256 + tid;
      int bb = f >> 5, q = f & 31;
      float4 v = *(const float4*)(in + (size_t)(bh * 64 + bb) * K + k0 + q * 4);
      lin4[bb * 32 + ((q & 24) | ((q ^ bb) & 7))] = v;
    }
    #pragma unroll
    for (int it = 0; it < 4; ++it) {
      int f = it * 256 + tid;
      int e = f >> 7, k = f & 127;
      float4 v = *(const float4*)(w + ((size_t)e * K + k0 + k) * HH_ + j0);
      ldsw[(e * 4 + 0) * 128 + k] = v.x;
      ldsw[(e * 4 + 1) * 128 + k] = v.y;
      ldsw[(e * 4 + 2) * 128 + k] = v.z;
      ldsw[(e * 4 + 3) * 128 + k] = v.w;
    }
    __syncthreads();
    #pragma unroll 2
    for (int q = 0; q < 32; ++q) {
      float4 xv = row4[(q & 24) | ((q ^ lane) & 7)];
      #pragma unroll
      for (int e = 0; e < E_; ++e) {
        const float4 wq = *(const float4*)&ldsw[(e * 4 + wv) * 128 + 4 * q];
        acc[e] = fmaf(xv.x, wq.x, acc[e]);
        acc[e] = fmaf(xv.y, wq.y, acc[e]);
        acc[e] = fmaf(xv.z, wq.z, acc[e]);
        acc[e] = fmaf(xv.w, wq.w, acc[e]);
      }
    }
  }

  float om[E_];
  #pragma unroll
  for (int e = 0; e < E_; ++e) om[e] = omega[b * E_ + e];
  float v = 0.f;
  #pragma unroll
  for (int e = 0; e < E_; ++e) v = fmaf(om[e], acc[e] + bias[e * HH_ + j], v);
  if (act == 0) v = (v > 0.f) ? v : expm1f(v);
  else          v = fminf(fmaxf(v, 0.f), 1.f);
  out[(size_t)b * HH_ + j] = v;
}

extern "C" void kernel_launch(void* const* d_in, const int* in_sizes, int n_in,
                              void* d_out, int out_size, void* d_ws, size_t ws_size,
                              hipStream_t stream) {
  (void)in_sizes; (void)n_in; (void)out_size;
  const float* X     = (const float*)d_in[0];
  const float* gwih0 = (const float*)d_in[1];
  const float* gwhh0 = (const float*)d_in[2];
  const float* gbih0 = (const float*)d_in[3];
  const float* gbhh0 = (const float*)d_in[4];
  const float* gwih1 = (const float*)d_in[5];
  const float* gwhh1 = (const float*)d_in[6];
  const float* gbih1 = (const float*)d_in[7];
  const float* gbhh1 = (const float*)d_in[8];
  const float* mwih  = (const float*)d_in[9];
  const float* mwhh  = (const float*)d_in[10];
  const float* mbih  = (const float*)d_in[11];
  const float* mbhh  = (const float*)d_in[12];
  const float* w1    = (const float*)d_in[13];
  const float* b1    = (const float*)d_in[14];
  const float* w2    = (const float*)d_in[15];
  const float* b2    = (const float*)d_in[16];
  const float* w3    = (const float*)d_in[17];
  const float* b3    = (const float*)d_in[18];

  float* ws = (float*)d_ws;
  unsigned* barr = (unsigned*)ws;                        // 256 slots reserved
  float* hA   = ws + 256;                                // h4T ping
  float* hB   = hA + (size_t)B_ * H_;                    // h4T pong
  float* hfin = hB + (size_t)B_ * H_;                    // [b][k]
  float* om   = hfin + (size_t)B_ * H_;
  float* a1   = om + B_ * GH_;
  float* a2   = a1 + (size_t)B_ * HH_;
  float* XT   = a2 + (size_t)B_ * HH_;                   // [t][k/4][b] float4
  size_t base_floats = 256 + 3 * (size_t)B_ * H_ + B_ * GH_ + 2 * (size_t)B_ * HH_;
  size_t xt_floats   = (size_t)T_ * IN_ * B_;
  int use_xt = (ws_size >= (base_floats + xt_floats) * sizeof(float)) ? 1 : 0;

  hipMemsetAsync(d_ws, 0, (256 + (size_t)B_ * H_) * sizeof(float), stream);
  hipFuncSetAttribute((const void*)gru_persist,
                      hipFuncAttributeMaxDynamicSharedMemorySize, 90112);

  gating_kernel<<<128, 64, 0, stream>>>(X, gwih0, gwhh0, gbih0, gbhh0,
                                        gwih1, gwhh1, gbih1, gbhh1, om);
  if (use_xt)
    xt_kernel<<<(T_ * 128 * 128) / 256, 256, 0, stream>>>(X, (float4*)XT);
  gru_persist<<<256, 512, 90112, stream>>>(X, (const float4*)XT, use_xt,
                                           mwih, mwhh, mbih, mbhh, hA, hB, barr);
  hfin_kernel<<<512, 256, 0, stream>>>(hA, hfin);
  moe_kernel<<<256, 256, 0, stream>>>(hfin, w1, b1, om, a1, H_, 0);
  moe_kernel<<<256, 256, 0, stream>>>(a1, w2, b2, om, a2, HH_, 0);
  moe_kernel<<<256, 256, 0, stream>>>(a2, w3, b3, om, (float*)d_out, HH_, 1);
}

// Round 4
// 5336.266 us; speedup vs baseline: 1.7283x; 1.4603x over previous
//
#include <hip/hip_runtime.h>
#include <cmath>

#define B_   128
#define T_   100
#define IN_  512
#define H_   1024
#define E_   8
#define HH_  512
#define GIN_ 5
#define GH_  8

__device__ __forceinline__ float sigf(float x) { return 1.0f / (1.0f + expf(-x)); }

#define DOT4(a, xv, wv)                                              \
  a = fmaf((xv).x, (wv).x, a); a = fmaf((xv).y, (wv).y, a);          \
  a = fmaf((xv).z, (wv).z, a); a = fmaf((xv).w, (wv).w, a);

__device__ __forceinline__ void gridbar(unsigned* c) {
  __syncthreads();
  if (threadIdx.x == 0) {
    __threadfence();   // release: push h stores through L2 -> LLC
    __hip_atomic_fetch_add(c, 1u, __ATOMIC_RELAXED, __HIP_MEMORY_SCOPE_AGENT);
    while (__hip_atomic_load(c, __ATOMIC_RELAXED, __HIP_MEMORY_SCOPE_AGENT) < gridDim.x) {
      __builtin_amdgcn_s_sleep(1);
    }
    __threadfence();   // acquire: invalidate L1/L2 so remote h writes are seen
  }
  __syncthreads();
}

// Transpose X[b][t][0:512] -> XT4[t][kq][b] (float4 per (kq,b)).
__global__ __launch_bounds__(256) void xt_kernel(
    const float* __restrict__ X, float4* __restrict__ XT4)
{
  int idx = blockIdx.x * 256 + threadIdx.x;     // over 100*128*128
  int b  = idx & 127;
  int kq = (idx >> 7) & 127;
  int t  = idx >> 14;
  XT4[idx] = *(const float4*)(X + ((size_t)b * T_ + t) * IN_ + kq * 4);
}

// uniform weight-row float4 pointers (compiler scalarizes loads -> s_load)
#define ROWX(g, jj) ((const float4*)(wih) + (((size_t)((g) * H_ + j0 + (jj))) << 7))
#define ROWH(g, jj) ((const float4*)(whh) + (((size_t)((g) * H_ + j0 + (jj))) << 8))

// Persistent main GRU: 256 blocks x 1024 threads (16 waves, 4/SIMD), 1 block/CU.
// Block: 4 j-cols x 128 batches; waves k-split 16 ways (no redundant x/h reads).
// Weights stream via scalar loads (wave-uniform addresses, L2-hot).
__global__ __launch_bounds__(1024, 4) void gru_persist(
    const float* __restrict__ X, const float4* __restrict__ XT4, int use_xt,
    const float* __restrict__ wih, const float* __restrict__ whh,
    const float* __restrict__ bih, const float* __restrict__ bhh,
    float* __restrict__ hA, float* __restrict__ hB,   // h4T [H/4][128] float4
    unsigned* __restrict__ barr)
{
  extern __shared__ float4 red4[];                    // [16][4][128] = 128 KB

  const int tid  = threadIdx.x;
  const int lane = tid & 63;
  const int ks   = __builtin_amdgcn_readfirstlane(tid >> 6);   // 0..15
  const int j0   = blockIdx.x << 2;

  // epilogue mapping + biases (threads 0..511 only; ks<8 -> wave-uniform branch)
  const int ej = tid >> 7;          // jl 0..3  (valid when tid<512)
  const int eb = tid & 127;
  float bir = 0.f, biz = 0.f, bin = 0.f, bhr = 0.f, bhz = 0.f, bhn = 0.f;
  if (tid < 512) {
    const int j = j0 + ej;
    bir = bih[j]; biz = bih[H_ + j]; bin = bih[2 * H_ + j];
    bhr = bhh[j]; bhz = bhh[H_ + j]; bhn = bhh[2 * H_ + j];
  }

  for (int t = 0; t < T_; ++t) {
    const float4* __restrict__ hp4 = (const float4*)((t & 1) ? hB : hA);
    float*        __restrict__ hn  = (t & 1) ? hA : hB;

    float aR[4][2] = {}, aZ[4][2] = {}, aNX[4][2] = {}, aNH[4][2] = {};

    // ---- X phase: x-quads ks*8 .. ks*8+7  (128 quads over 16 waves)
    if (use_xt) {
      const float4* __restrict__ xt = XT4 + (size_t)t * (128 * 128);
      int q = ks * 8;
      float4 x0 = xt[q * 128 + lane];
      float4 x1 = xt[q * 128 + lane + 64];
      #pragma unroll
      for (int i = 0; i < 8; ++i) {
        float4 p0 = x0, p1 = x1;
        if (i < 7) { p0 = xt[(q + 1) * 128 + lane]; p1 = xt[(q + 1) * 128 + lane + 64]; }
        #pragma unroll
        for (int g = 0; g < 3; ++g) {
          #pragma unroll
          for (int jj = 0; jj < 4; ++jj) {
            const float4 w = ROWX(g, jj)[q];
            float& A0 = (g == 0) ? aR[jj][0] : (g == 1) ? aZ[jj][0] : aNX[jj][0];
            float& A1 = (g == 0) ? aR[jj][1] : (g == 1) ? aZ[jj][1] : aNX[jj][1];
            DOT4(A0, x0, w); DOT4(A1, x1, w);
          }
        }
        x0 = p0; x1 = p1; ++q;
      }
    } else {
      const float* xr0 = X + ((size_t)lane * T_ + t) * IN_;
      const float* xr1 = X + ((size_t)(lane + 64) * T_ + t) * IN_;
      for (int q = ks * 8; q < ks * 8 + 8; ++q) {
        float4 x0 = *(const float4*)(xr0 + q * 4);
        float4 x1 = *(const float4*)(xr1 + q * 4);
        #pragma unroll
        for (int g = 0; g < 3; ++g) {
          #pragma unroll
          for (int jj = 0; jj < 4; ++jj) {
            const float4 w = ROWX(g, jj)[q];
            float& A0 = (g == 0) ? aR[jj][0] : (g == 1) ? aZ[jj][0] : aNX[jj][0];
            float& A1 = (g == 0) ? aR[jj][1] : (g == 1) ? aZ[jj][1] : aNX[jj][1];
            DOT4(A0, x0, w); DOT4(A1, x1, w);
          }
        }
      }
    }

    // ---- H phase: h-quads ks*16 .. ks*16+15  (256 quads over 16 waves)
    {
      int q = ks * 16;
      float4 x0 = hp4[q * 128 + lane];
      float4 x1 = hp4[q * 128 + lane + 64];
      #pragma unroll
      for (int i = 0; i < 16; ++i) {
        float4 p0 = x0, p1 = x1;
        if (i < 15) { p0 = hp4[(q + 1) * 128 + lane]; p1 = hp4[(q + 1) * 128 + lane + 64]; }
        #pragma unroll
        for (int g = 0; g < 3; ++g) {
          #pragma unroll
          for (int jj = 0; jj < 4; ++jj) {
            const float4 w = ROWH(g, jj)[q];
            float& A0 = (g == 0) ? aR[jj][0] : (g == 1) ? aZ[jj][0] : aNH[jj][0];
            float& A1 = (g == 0) ? aR[jj][1] : (g == 1) ? aZ[jj][1] : aNH[jj][1];
            DOT4(A0, x0, w); DOT4(A1, x1, w);
          }
        }
        x0 = p0; x1 = p1; ++q;
      }
    }

    // ---- 16-way cross-wave K reduction via LDS
    #pragma unroll
    for (int jj = 0; jj < 4; ++jj) {
      red4[(ks * 4 + jj) * 128 + lane]      = make_float4(aR[jj][0], aZ[jj][0], aNX[jj][0], aNH[jj][0]);
      red4[(ks * 4 + jj) * 128 + lane + 64] = make_float4(aR[jj][1], aZ[jj][1], aNX[jj][1], aNH[jj][1]);
    }
    __syncthreads();

    if (tid < 512) {
      float sr = 0.f, sz = 0.f, sx = 0.f, sh = 0.f;
      #pragma unroll
      for (int k2 = 0; k2 < 16; ++k2) {
        float4 v = red4[(k2 * 4 + ej) * 128 + eb];
        sr += v.x; sz += v.y; sx += v.z; sh += v.w;
      }
      float r = sigf(sr + bir + bhr);
      float z = sigf(sz + biz + bhz);
      float n = tanhf(sx + bin + r * (sh + bhn));
      int hidx = ((blockIdx.x * 128 + eb) << 2) + ej;
      float hpv = ((const float*)hp4)[hidx];
      hn[hidx] = (1.f - z) * n + z * hpv;
    }

    gridbar(barr + t);   // trailing syncthreads protects red4 reuse next step
  }
}

// Final h4T -> hfin[b][k]
__global__ __launch_bounds__(256) void hfin_kernel(
    const float* __restrict__ h4, float* __restrict__ out)
{
  int idx = blockIdx.x * 256 + threadIdx.x;   // over 128*1024
  int b = idx >> 10, k = idx & 1023;
  out[idx] = h4[(((k >> 2) * 128 + b) << 2) + (k & 3)];
}

// Gating GRUs: one wave per batch, gate-per-lane (24 gates), all state in regs.
__global__ __launch_bounds__(64, 1) void gating_kernel(
    const float* __restrict__ X,
    const float* __restrict__ gwih0, const float* __restrict__ gwhh0,
    const float* __restrict__ gbih0, const float* __restrict__ gbhh0,
    const float* __restrict__ gwih1, const float* __restrict__ gwhh1,
    const float* __restrict__ gbih1, const float* __restrict__ gbhh1,
    float* __restrict__ omega)
{
  const int b = blockIdx.x;
  const int g = threadIdx.x;
  const int u = g & 7;
  float wi0[GIN_] = {}, wh0[GH_] = {}, wi1[GH_] = {}, wh1[GH_] = {};
  float bi0 = 0.f, bh0 = 0.f, bi1 = 0.f, bh1 = 0.f;
  if (g < 3 * GH_) {
    #pragma unroll
    for (int i = 0; i < GIN_; ++i) wi0[i] = gwih0[g * GIN_ + i];
    #pragma unroll
    for (int k = 0; k < GH_; ++k) { wh0[k] = gwhh0[g * GH_ + k]; wi1[k] = gwih1[g * GH_ + k]; wh1[k] = gwhh1[g * GH_ + k]; }
    bi0 = gbih0[g]; bh0 = gbhh0[g]; bi1 = gbih1[g]; bh1 = gbhh1[g];
  }
  float h0[GH_] = {}, h1[GH_] = {};
  for (int t = 0; t < T_; ++t) {
    float xt[GIN_];
    #pragma unroll
    for (int i = 0; i < GIN_; ++i) xt[i] = X[((size_t)b * T_ + t) * IN_ + (IN_ - GIN_) + i];
    float px = bi0, ph = bh0;
    #pragma unroll
    for (int i = 0; i < GIN_; ++i) px = fmaf(xt[i], wi0[i], px);
    #pragma unroll
    for (int k = 0; k < GH_; ++k) ph = fmaf(h0[k], wh0[k], ph);
    float s = px + ph;
    float s_r = __shfl(s, u);
    float s_z = __shfl(s, 8 + u);
    float nval = tanhf(px + sigf(s_r) * ph);
    float zval = sigf(s_z);
    float hnew = (1.f - zval) * nval + zval * h0[u];
    #pragma unroll
    for (int k = 0; k < GH_; ++k) h0[k] = __shfl(hnew, 16 + k);
    float px1 = bi1, ph1 = bh1;
    #pragma unroll
    for (int k = 0; k < GH_; ++k) px1 = fmaf(h0[k], wi1[k], px1);
    #pragma unroll
    for (int k = 0; k < GH_; ++k) ph1 = fmaf(h1[k], wh1[k], ph1);
    float s1 = px1 + ph1;
    float s1r = __shfl(s1, u);
    float s1z = __shfl(s1, 8 + u);
    float n1 = tanhf(px1 + sigf(s1r) * ph1);
    float z1 = sigf(s1z);
    float h1new = (1.f - z1) * n1 + z1 * h1[u];
    #pragma unroll
    for (int k = 0; k < GH_; ++k) h1[k] = __shfl(h1new, 16 + k);
  }
  if (g < GH_) {
    float m = h1[0];
    #pragma unroll
    for (int k = 1; k < GH_; ++k) m = fmaxf(m, h1[k]);
    float sum = 0.f;
    #pragma unroll
    for (int k = 0; k < GH_; ++k) sum += expf(h1[k] - m);
    omega[b * GH_ + g] = expf(h1[g] - m) / sum;
  }
}

// MoE layer: out[b,j] = act( sum_e omega[b,e] * (dot(in[b,:],w[e,:,j]) + bias[e,j]) )
__global__ __launch_bounds__(256, 2) void moe_kernel(
    const float* __restrict__ in, const float* __restrict__ w,
    const float* __restrict__ bias, const float* __restrict__ omega,
    float* __restrict__ out, int K, int act)
{
  __shared__ float4 lin4[64 * 32];
  __shared__ float  ldsw[E_ * 4 * 128];
  const int tid  = threadIdx.x;
  const int bh   = blockIdx.x & 1;
  const int jt   = blockIdx.x >> 1;
  const int wv   = tid >> 6;
  const int lane = tid & 63;
  const int j0   = jt * 4;
  const int j    = __builtin_amdgcn_readfirstlane(j0 + wv);
  const int b    = bh * 64 + lane;

  float acc[E_] = {0.f,0.f,0.f,0.f,0.f,0.f,0.f,0.f};
  const float4* row4 = &lin4[lane * 32];
  const int nch = K / 128;

  for (int c = 0; c < nch; ++c) {
    __syncthreads();
    const int k0 = c * 128;
    #pragma unroll
    for (int it = 0; it < 8; ++it) {
      int f = it * 256 + tid;
      int bb = f >> 5, q = f & 31;
      float4 v = *(const float4*)(in + (size_t)(bh * 64 + bb) * K + k0 + q * 4);
      lin4[bb * 32 + ((q & 24) | ((q ^ bb) & 7))] = v;
    }
    #pragma unroll
    for (int it = 0; it < 4; ++it) {
      int f = it * 256 + tid;
      int e = f >> 7, k = f & 127;
      float4 v = *(const float4*)(w + ((size_t)e * K + k0 + k) * HH_ + j0);
      ldsw[(e * 4 + 0) * 128 + k] = v.x;
      ldsw[(e * 4 + 1) * 128 + k] = v.y;
      ldsw[(e * 4 + 2) * 128 + k] = v.z;
      ldsw[(e * 4 + 3) * 128 + k] = v.w;
    }
    __syncthreads();
    #pragma unroll 2
    for (int q = 0; q < 32; ++q) {
      float4 xv = row4[(q & 24) | ((q ^ lane) & 7)];
      #pragma unroll
      for (int e = 0; e < E_; ++e) {
        const float4 wq = *(const float4*)&ldsw[(e * 4 + wv) * 128 + 4 * q];
        acc[e] = fmaf(xv.x, wq.x, acc[e]);
        acc[e] = fmaf(xv.y, wq.y, acc[e]);
        acc[e] = fmaf(xv.z, wq.z, acc[e]);
        acc[e] = fmaf(xv.w, wq.w, acc[e]);
      }
    }
  }

  float om[E_];
  #pragma unroll
  for (int e = 0; e < E_; ++e) om[e] = omega[b * E_ + e];
  float v = 0.f;
  #pragma unroll
  for (int e = 0; e < E_; ++e) v = fmaf(om[e], acc[e] + bias[e * HH_ + j], v);
  if (act == 0) v = (v > 0.f) ? v : expm1f(v);
  else          v = fminf(fmaxf(v, 0.f), 1.f);
  out[(size_t)b * HH_ + j] = v;
}

extern "C" void kernel_launch(void* const* d_in, const int* in_sizes, int n_in,
                              void* d_out, int out_size, void* d_ws, size_t ws_size,
                              hipStream_t stream) {
  (void)in_sizes; (void)n_in; (void)out_size;
  const float* X     = (const float*)d_in[0];
  const float* gwih0 = (const float*)d_in[1];
  const float* gwhh0 = (const float*)d_in[2];
  const float* gbih0 = (const float*)d_in[3];
  const float* gbhh0 = (const float*)d_in[4];
  const float* gwih1 = (const float*)d_in[5];
  const float* gwhh1 = (const float*)d_in[6];
  const float* gbih1 = (const float*)d_in[7];
  const float* gbhh1 = (const float*)d_in[8];
  const float* mwih  = (const float*)d_in[9];
  const float* mwhh  = (const float*)d_in[10];
  const float* mbih  = (const float*)d_in[11];
  const float* mbhh  = (const float*)d_in[12];
  const float* w1    = (const float*)d_in[13];
  const float* b1    = (const float*)d_in[14];
  const float* w2    = (const float*)d_in[15];
  const float* b2    = (const float*)d_in[16];
  const float* w3    = (const float*)d_in[17];
  const float* b3    = (const float*)d_in[18];

  float* ws = (float*)d_ws;
  unsigned* barr = (unsigned*)ws;                        // 256 slots reserved
  float* hA   = ws + 256;                                // h4T ping
  float* hB   = hA + (size_t)B_ * H_;                    // h4T pong
  float* hfin = hB + (size_t)B_ * H_;                    // [b][k]
  float* om   = hfin + (size_t)B_ * H_;
  float* a1   = om + B_ * GH_;
  float* a2   = a1 + (size_t)B_ * HH_;
  float* XT   = a2 + (size_t)B_ * HH_;                   // [t][k/4][b] float4
  size_t base_floats = 256 + 3 * (size_t)B_ * H_ + B_ * GH_ + 2 * (size_t)B_ * HH_;
  size_t xt_floats   = (size_t)T_ * IN_ * B_;
  int use_xt = (ws_size >= (base_floats + xt_floats) * sizeof(float)) ? 1 : 0;

  hipMemsetAsync(d_ws, 0, (256 + (size_t)B_ * H_) * sizeof(float), stream);
  hipFuncSetAttribute((const void*)gru_persist,
                      hipFuncAttributeMaxDynamicSharedMemorySize, 131072);

  gating_kernel<<<128, 64, 0, stream>>>(X, gwih0, gwhh0, gbih0, gbhh0,
                                        gwih1, gwhh1, gbih1, gbhh1, om);
  if (use_xt)
    xt_kernel<<<(T_ * 128 * 128) / 256, 256, 0, stream>>>(X, (float4*)XT);
  gru_persist<<<256, 1024, 131072, stream>>>(X, (const float4*)XT, use_xt,
                                             mwih, mwhh, mbih, mbhh, hA, hB, barr);
  hfin_kernel<<<512, 256, 0, stream>>>(hA, hfin);
  moe_kernel<<<256, 256, 0, stream>>>(hfin, w1, b1, om, a1, H_, 0);
  moe_kernel<<<256, 256, 0, stream>>>(a1, w2, b2, om, a2, HH_, 0);
  moe_kernel<<<256, 256, 0, stream>>>(a2, w3, b3, om, (float*)d_out, HH_, 1);
}

// Round 5
// 4530.874 us; speedup vs baseline: 2.0355x; 1.1778x over previous
//
#include <hip/hip_runtime.h>
#include <cmath>

#define B_   128
#define T_   100
#define IN_  512
#define H_   1024
#define E_   8
#define HH_  512
#define GIN_ 5
#define GH_  8

typedef unsigned long long u64t;

__device__ __forceinline__ float sigf(float x) { return 1.0f / (1.0f + expf(-x)); }

#define DOT4(a, xv, wv)                                              \
  a = fmaf((xv).x, (wv).x, a); a = fmaf((xv).y, (wv).y, a);          \
  a = fmaf((xv).z, (wv).z, a); a = fmaf((xv).w, (wv).w, a);

// Device-coherent (agent-scope, sc1) 16B h-load as two u64 atomic loads.
// Bypasses the stale per-XCD L2; served by the LLC coherence point.
__device__ __forceinline__ float4 ld_h4(const float4* p) {
  const u64t* q = (const u64t*)p;
  u64t a = __hip_atomic_load(q,     __ATOMIC_RELAXED, __HIP_MEMORY_SCOPE_AGENT);
  u64t b = __hip_atomic_load(q + 1, __ATOMIC_RELAXED, __HIP_MEMORY_SCOPE_AGENT);
  union { u64t u; float2 f; } ca, cb;
  ca.u = a; cb.u = b;
  return make_float4(ca.f.x, ca.f.y, cb.f.x, cb.f.y);
}

// Grid barrier WITHOUT cache invalidation: h traffic is itself agent-coherent,
// so no __threadfence (which would invalidate L2 and evict hot weights).
__device__ __forceinline__ void gridbar(unsigned* c) {
  __syncthreads();   // drains vmcnt: all sc1 h-stores have reached the LLC
  if (threadIdx.x == 0) {
    __hip_atomic_fetch_add(c, 1u, __ATOMIC_RELEASE, __HIP_MEMORY_SCOPE_AGENT);
    while (__hip_atomic_load(c, __ATOMIC_RELAXED, __HIP_MEMORY_SCOPE_AGENT) < gridDim.x) {
      __builtin_amdgcn_s_sleep(1);
    }
  }
  __syncthreads();
}

// Transpose X[b][t][0:512] -> XT4[t][kq][b] (float4 per (kq,b)).
__global__ __launch_bounds__(256) void xt_kernel(
    const float* __restrict__ X, float4* __restrict__ XT4)
{
  int idx = blockIdx.x * 256 + threadIdx.x;     // over 100*128*128
  int b  = idx & 127;
  int kq = (idx >> 7) & 127;
  int t  = idx >> 14;
  XT4[idx] = *(const float4*)(X + ((size_t)b * T_ + t) * IN_ + kq * 4);
}

// uniform weight-row float4 pointers (compiler scalarizes loads -> s_load)
#define ROWX(g, jj) ((const float4*)(wih) + (((size_t)((g) * H_ + j0 + (jj))) << 7))
#define ROWH(g, jj) ((const float4*)(whh) + (((size_t)((g) * H_ + j0 + (jj))) << 8))

// Persistent main GRU: 256 blocks x 1024 threads (16 waves, 4/SIMD), 1 block/CU.
// Block: 4 j-cols x 128 batches; waves k-split 16 ways.
// Weights/X: normal cached loads (L2 stays warm — never invalidated).
// h ping-pong: agent-scope (sc1) loads/stores through the LLC.
__global__ __launch_bounds__(1024, 4) void gru_persist(
    const float* __restrict__ X, const float4* __restrict__ XT4, int use_xt,
    const float* __restrict__ wih, const float* __restrict__ whh,
    const float* __restrict__ bih, const float* __restrict__ bhh,
    float* __restrict__ hA, float* __restrict__ hB,   // h4T [H/4][128] float4
    unsigned* __restrict__ barr)
{
  extern __shared__ float4 red4[];                    // [16][4][128] = 128 KB

  const int tid  = threadIdx.x;
  const int lane = tid & 63;
  const int ks   = __builtin_amdgcn_readfirstlane(tid >> 6);   // 0..15
  const int j0   = blockIdx.x << 2;

  // epilogue mapping + biases (threads 0..511 only)
  const int ej = tid >> 7;          // jl 0..3  (valid when tid<512)
  const int eb = tid & 127;
  float bir = 0.f, biz = 0.f, bin = 0.f, bhr = 0.f, bhz = 0.f, bhn = 0.f;
  if (tid < 512) {
    const int j = j0 + ej;
    bir = bih[j]; biz = bih[H_ + j]; bin = bih[2 * H_ + j];
    bhr = bhh[j]; bhz = bhh[H_ + j]; bhn = bhh[2 * H_ + j];
  }

  for (int t = 0; t < T_; ++t) {
    const float4* __restrict__ hp4 = (const float4*)((t & 1) ? hB : hA);
    float*        __restrict__ hn  = (t & 1) ? hA : hB;

    float aR[4][2] = {}, aZ[4][2] = {}, aNX[4][2] = {}, aNH[4][2] = {};

    // ---- X phase: x-quads ks*8 .. ks*8+7  (128 quads over 16 waves)
    if (use_xt) {
      const float4* __restrict__ xt = XT4 + (size_t)t * (128 * 128);
      int q = ks * 8;
      float4 x0 = xt[q * 128 + lane];
      float4 x1 = xt[q * 128 + lane + 64];
      #pragma unroll
      for (int i = 0; i < 8; ++i) {
        float4 p0 = x0, p1 = x1;
        if (i < 7) { p0 = xt[(q + 1) * 128 + lane]; p1 = xt[(q + 1) * 128 + lane + 64]; }
        #pragma unroll
        for (int g = 0; g < 3; ++g) {
          #pragma unroll
          for (int jj = 0; jj < 4; ++jj) {
            const float4 w = ROWX(g, jj)[q];
            float& A0 = (g == 0) ? aR[jj][0] : (g == 1) ? aZ[jj][0] : aNX[jj][0];
            float& A1 = (g == 0) ? aR[jj][1] : (g == 1) ? aZ[jj][1] : aNX[jj][1];
            DOT4(A0, x0, w); DOT4(A1, x1, w);
          }
        }
        x0 = p0; x1 = p1; ++q;
      }
    } else {
      const float* xr0 = X + ((size_t)lane * T_ + t) * IN_;
      const float* xr1 = X + ((size_t)(lane + 64) * T_ + t) * IN_;
      for (int q = ks * 8; q < ks * 8 + 8; ++q) {
        float4 x0 = *(const float4*)(xr0 + q * 4);
        float4 x1 = *(const float4*)(xr1 + q * 4);
        #pragma unroll
        for (int g = 0; g < 3; ++g) {
          #pragma unroll
          for (int jj = 0; jj < 4; ++jj) {
            const float4 w = ROWX(g, jj)[q];
            float& A0 = (g == 0) ? aR[jj][0] : (g == 1) ? aZ[jj][0] : aNX[jj][0];
            float& A1 = (g == 0) ? aR[jj][1] : (g == 1) ? aZ[jj][1] : aNX[jj][1];
            DOT4(A0, x0, w); DOT4(A1, x1, w);
          }
        }
      }
    }

    // ---- H phase: h-quads ks*16 .. ks*16+15 (sc1 coherent loads)
    {
      int q = ks * 16;
      float4 x0 = ld_h4(&hp4[q * 128 + lane]);
      float4 x1 = ld_h4(&hp4[q * 128 + lane + 64]);
      #pragma unroll
      for (int i = 0; i < 16; ++i) {
        float4 p0 = x0, p1 = x1;
        if (i < 15) {
          p0 = ld_h4(&hp4[(q + 1) * 128 + lane]);
          p1 = ld_h4(&hp4[(q + 1) * 128 + lane + 64]);
        }
        #pragma unroll
        for (int g = 0; g < 3; ++g) {
          #pragma unroll
          for (int jj = 0; jj < 4; ++jj) {
            const float4 w = ROWH(g, jj)[q];
            float& A0 = (g == 0) ? aR[jj][0] : (g == 1) ? aZ[jj][0] : aNH[jj][0];
            float& A1 = (g == 0) ? aR[jj][1] : (g == 1) ? aZ[jj][1] : aNH[jj][1];
            DOT4(A0, x0, w); DOT4(A1, x1, w);
          }
        }
        x0 = p0; x1 = p1; ++q;
      }
    }

    // ---- 16-way cross-wave K reduction via LDS
    #pragma unroll
    for (int jj = 0; jj < 4; ++jj) {
      red4[(ks * 4 + jj) * 128 + lane]      = make_float4(aR[jj][0], aZ[jj][0], aNX[jj][0], aNH[jj][0]);
      red4[(ks * 4 + jj) * 128 + lane + 64] = make_float4(aR[jj][1], aZ[jj][1], aNX[jj][1], aNH[jj][1]);
    }
    __syncthreads();

    if (tid < 512) {
      float sr = 0.f, sz = 0.f, sx = 0.f, sh = 0.f;
      #pragma unroll
      for (int k2 = 0; k2 < 16; ++k2) {
        float4 v = red4[(k2 * 4 + ej) * 128 + eb];
        sr += v.x; sz += v.y; sx += v.z; sh += v.w;
      }
      float r = sigf(sr + bir + bhr);
      float z = sigf(sz + biz + bhz);
      float n = tanhf(sx + bin + r * (sh + bhn));
      int hidx = ((blockIdx.x * 128 + eb) << 2) + ej;
      float hpv = __hip_atomic_load(&((const float*)hp4)[hidx],
                                    __ATOMIC_RELAXED, __HIP_MEMORY_SCOPE_AGENT);
      float hv = (1.f - z) * n + z * hpv;
      __hip_atomic_store(&hn[hidx], hv, __ATOMIC_RELAXED, __HIP_MEMORY_SCOPE_AGENT);
    }

    gridbar(barr + t);   // trailing syncthreads protects red4 reuse next step
  }
}

// Final h4T -> hfin[b][k]
__global__ __launch_bounds__(256) void hfin_kernel(
    const float* __restrict__ h4, float* __restrict__ out)
{
  int idx = blockIdx.x * 256 + threadIdx.x;   // over 128*1024
  int b = idx >> 10, k = idx & 1023;
  out[idx] = h4[(((k >> 2) * 128 + b) << 2) + (k & 3)];
}

// Gating GRUs: one wave per batch, gate-per-lane (24 gates), all state in regs.
__global__ __launch_bounds__(64, 1) void gating_kernel(
    const float* __restrict__ X,
    const float* __restrict__ gwih0, const float* __restrict__ gwhh0,
    const float* __restrict__ gbih0, const float* __restrict__ gbhh0,
    const float* __restrict__ gwih1, const float* __restrict__ gwhh1,
    const float* __restrict__ gbih1, const float* __restrict__ gbhh1,
    float* __restrict__ omega)
{
  const int b = blockIdx.x;
  const int g = threadIdx.x;
  const int u = g & 7;
  float wi0[GIN_] = {}, wh0[GH_] = {}, wi1[GH_] = {}, wh1[GH_] = {};
  float bi0 = 0.f, bh0 = 0.f, bi1 = 0.f, bh1 = 0.f;
  if (g < 3 * GH_) {
    #pragma unroll
    for (int i = 0; i < GIN_; ++i) wi0[i] = gwih0[g * GIN_ + i];
    #pragma unroll
    for (int k = 0; k < GH_; ++k) { wh0[k] = gwhh0[g * GH_ + k]; wi1[k] = gwih1[g * GH_ + k]; wh1[k] = gwhh1[g * GH_ + k]; }
    bi0 = gbih0[g]; bh0 = gbhh0[g]; bi1 = gbih1[g]; bh1 = gbhh1[g];
  }
  float h0[GH_] = {}, h1[GH_] = {};
  for (int t = 0; t < T_; ++t) {
    float xt[GIN_];
    #pragma unroll
    for (int i = 0; i < GIN_; ++i) xt[i] = X[((size_t)b * T_ + t) * IN_ + (IN_ - GIN_) + i];
    float px = bi0, ph = bh0;
    #pragma unroll
    for (int i = 0; i < GIN_; ++i) px = fmaf(xt[i], wi0[i], px);
    #pragma unroll
    for (int k = 0; k < GH_; ++k) ph = fmaf(h0[k], wh0[k], ph);
    float s = px + ph;
    float s_r = __shfl(s, u);
    float s_z = __shfl(s, 8 + u);
    float nval = tanhf(px + sigf(s_r) * ph);
    float zval = sigf(s_z);
    float hnew = (1.f - zval) * nval + zval * h0[u];
    #pragma unroll
    for (int k = 0; k < GH_; ++k) h0[k] = __shfl(hnew, 16 + k);
    float px1 = bi1, ph1 = bh1;
    #pragma unroll
    for (int k = 0; k < GH_; ++k) px1 = fmaf(h0[k], wi1[k], px1);
    #pragma unroll
    for (int k = 0; k < GH_; ++k) ph1 = fmaf(h1[k], wh1[k], ph1);
    float s1 = px1 + ph1;
    float s1r = __shfl(s1, u);
    float s1z = __shfl(s1, 8 + u);
    float n1 = tanhf(px1 + sigf(s1r) * ph1);
    float z1 = sigf(s1z);
    float h1new = (1.f - z1) * n1 + z1 * h1[u];
    #pragma unroll
    for (int k = 0; k < GH_; ++k) h1[k] = __shfl(h1new, 16 + k);
  }
  if (g < GH_) {
    float m = h1[0];
    #pragma unroll
    for (int k = 1; k < GH_; ++k) m = fmaxf(m, h1[k]);
    float sum = 0.f;
    #pragma unroll
    for (int k = 0; k < GH_; ++k) sum += expf(h1[k] - m);
    omega[b * GH_ + g] = expf(h1[g] - m) / sum;
  }
}

// MoE layer: out[b,j] = act( sum_e omega[b,e] * (dot(in[b,:],w[e,:,j]) + bias[e,j]) )
__global__ __launch_bounds__(256, 2) void moe_kernel(
    const float* __restrict__ in, const float* __restrict__ w,
    const float* __restrict__ bias, const float* __restrict__ omega,
    float* __restrict__ out, int K, int act)
{
  __shared__ float4 lin4[64 * 32];
  __shared__ float  ldsw[E_ * 4 * 128];
  const int tid  = threadIdx.x;
  const int bh   = blockIdx.x & 1;
  const int jt   = blockIdx.x >> 1;
  const int wv   = tid >> 6;
  const int lane = tid & 63;
  const int j0   = jt * 4;
  const int j    = __builtin_amdgcn_readfirstlane(j0 + wv);
  const int b    = bh * 64 + lane;

  float acc[E_] = {0.f,0.f,0.f,0.f,0.f,0.f,0.f,0.f};
  const float4* row4 = &lin4[lane * 32];
  const int nch = K / 128;

  for (int c = 0; c < nch; ++c) {
    __syncthreads();
    const int k0 = c * 128;
    #pragma unroll
    for (int it = 0; it < 8; ++it) {
      int f = it * 256 + tid;
      int bb = f >> 5, q = f & 31;
      float4 v = *(const float4*)(in + (size_t)(bh * 64 + bb) * K + k0 + q * 4);
      lin4[bb * 32 + ((q & 24) | ((q ^ bb) & 7))] = v;
    }
    #pragma unroll
    for (int it = 0; it < 4; ++it) {
      int f = it * 256 + tid;
      int e = f >> 7, k = f & 127;
      float4 v = *(const float4*)(w + ((size_t)e * K + k0 + k) * HH_ + j0);
      ldsw[(e * 4 + 0) * 128 + k] = v.x;
      ldsw[(e * 4 + 1) * 128 + k] = v.y;
      ldsw[(e * 4 + 2) * 128 + k] = v.z;
      ldsw[(e * 4 + 3) * 128 + k] = v.w;
    }
    __syncthreads();
    #pragma unroll 2
    for (int q = 0; q < 32; ++q) {
      float4 xv = row4[(q & 24) | ((q ^ lane) & 7)];
      #pragma unroll
      for (int e = 0; e < E_; ++e) {
        const float4 wq = *(const float4*)&ldsw[(e * 4 + wv) * 128 + 4 * q];
        acc[e] = fmaf(xv.x, wq.x, acc[e]);
        acc[e] = fmaf(xv.y, wq.y, acc[e]);
        acc[e] = fmaf(xv.z, wq.z, acc[e]);
        acc[e] = fmaf(xv.w, wq.w, acc[e]);
      }
    }
  }

  float om[E_];
  #pragma unroll
  for (int e = 0; e < E_; ++e) om[e] = omega[b * E_ + e];
  float v = 0.f;
  #pragma unroll
  for (int e = 0; e < E_; ++e) v = fmaf(om[e], acc[e] + bias[e * HH_ + j], v);
  if (act == 0) v = (v > 0.f) ? v : expm1f(v);
  else          v = fminf(fmaxf(v, 0.f), 1.f);
  out[(size_t)b * HH_ + j] = v;
}

extern "C" void kernel_launch(void* const* d_in, const int* in_sizes, int n_in,
                              void* d_out, int out_size, void* d_ws, size_t ws_size,
                              hipStream_t stream) {
  (void)in_sizes; (void)n_in; (void)out_size;
  const float* X     = (const float*)d_in[0];
  const float* gwih0 = (const float*)d_in[1];
  const float* gwhh0 = (const float*)d_in[2];
  const float* gbih0 = (const float*)d_in[3];
  const float* gbhh0 = (const float*)d_in[4];
  const float* gwih1 = (const float*)d_in[5];
  const float* gwhh1 = (const float*)d_in[6];
  const float* gbih1 = (const float*)d_in[7];
  const float* gbhh1 = (const float*)d_in[8];
  const float* mwih  = (const float*)d_in[9];
  const float* mwhh  = (const float*)d_in[10];
  const float* mbih  = (const float*)d_in[11];
  const float* mbhh  = (const float*)d_in[12];
  const float* w1    = (const float*)d_in[13];
  const float* b1    = (const float*)d_in[14];
  const float* w2    = (const float*)d_in[15];
  const float* b2    = (const float*)d_in[16];
  const float* w3    = (const float*)d_in[17];
  const float* b3    = (const float*)d_in[18];

  float* ws = (float*)d_ws;
  unsigned* barr = (unsigned*)ws;                        // 256 slots reserved
  float* hA   = ws + 256;                                // h4T ping
  float* hB   = hA + (size_t)B_ * H_;                    // h4T pong
  float* hfin = hB + (size_t)B_ * H_;                    // [b][k]
  float* om   = hfin + (size_t)B_ * H_;
  float* a1   = om + B_ * GH_;
  float* a2   = a1 + (size_t)B_ * HH_;
  float* XT   = a2 + (size_t)B_ * HH_;                   // [t][k/4][b] float4
  size_t base_floats = 256 + 3 * (size_t)B_ * H_ + B_ * GH_ + 2 * (size_t)B_ * HH_;
  size_t xt_floats   = (size_t)T_ * IN_ * B_;
  int use_xt = (ws_size >= (base_floats + xt_floats) * sizeof(float)) ? 1 : 0;

  hipMemsetAsync(d_ws, 0, (256 + (size_t)B_ * H_) * sizeof(float), stream);
  hipFuncSetAttribute((const void*)gru_persist,
                      hipFuncAttributeMaxDynamicSharedMemorySize, 131072);

  gating_kernel<<<128, 64, 0, stream>>>(X, gwih0, gwhh0, gbih0, gbhh0,
                                        gwih1, gwhh1, gbih1, gbhh1, om);
  if (use_xt)
    xt_kernel<<<(T_ * 128 * 128) / 256, 256, 0, stream>>>(X, (float4*)XT);
  gru_persist<<<256, 1024, 131072, stream>>>(X, (const float4*)XT, use_xt,
                                             mwih, mwhh, mbih, mbhh, hA, hB, barr);
  hfin_kernel<<<512, 256, 0, stream>>>(hA, hfin);
  moe_kernel<<<256, 256, 0, stream>>>(hfin, w1, b1, om, a1, H_, 0);
  moe_kernel<<<256, 256, 0, stream>>>(a1, w2, b2, om, a2, HH_, 0);
  moe_kernel<<<256, 256, 0, stream>>>(a2, w3, b3, om, (float*)d_out, HH_, 1);
}